// Round 3
// baseline (83.933 us; speedup 1.0000x reference)
//
#include <hip/hip_runtime.h>

// labels[b,l,c] = argmin_q ( LN(t)[b,l,c] - LN(code_book)[c,q] )
//              = argmax_q LN(code_book)[c,q]        (tn constant along q)
//              = argmax_q code_book[c,q]            (global-scalar LN is monotone)
// => output is a 256-entry per-c label vector broadcast over (B, L).
//
// v3 (isolation A/B): revert NBLOCKS 256 -> 128 (the suspected regression:
// 256 blocks of uncoalesced cold-L2 reads of the same 256 KB codebook
// doubled TA/MSHR contention with zero latency hiding at 1 wave/SIMD).
// Keep the 4-way scan-chain split from v2 (thread-local, chain 256->64
// dependent steps, same memory pattern as the proven 68 µs v1).

#define C_DIM 256
#define Q_DIM 256
#define OUT_INT4 (4 * 512 * 256 / 4)   // B*L*C / 4 = 131072 int4 stores
#define NBLOCKS 128

__global__ __launch_bounds__(256) void rpq_fused(const float* __restrict__ cb,
                                                 int* __restrict__ out) {
    __shared__ int s[C_DIM];
    const int tid  = threadIdx.x;
    const int lane = tid & 63;

    const float4* row4 = (const float4*)(cb + tid * Q_DIM);

    // Four independent scan chains over contiguous quarters of the row.
    float best[4];
    int   bi[4];
#pragma unroll
    for (int k = 0; k < 4; ++k) {
        float b  = -3.4e38f;
        int   idx = 0;
#pragma unroll
        for (int j = 0; j < 16; ++j) {
            float4 v = row4[k * 16 + j];
            int q = (k * 16 + j) * 4;
            if (v.x > b) { b = v.x; idx = q; }
            if (v.y > b) { b = v.y; idx = q + 1; }
            if (v.z > b) { b = v.z; idx = q + 2; }
            if (v.w > b) { b = v.w; idx = q + 3; }
        }
        best[k] = b;
        bi[k]   = idx;
    }
    // Merge in ascending quarter order; strict '>' keeps the earliest index
    // on ties, reproducing jnp.argmin's first-index tie-breaking.
    float b  = best[0];
    int   idx = bi[0];
    if (best[1] > b) { b = best[1]; idx = bi[1]; }
    if (best[2] > b) { b = best[2]; idx = bi[2]; }
    if (best[3] > b) { b = best[3]; idx = bi[3]; }

    s[tid] = idx;
    __syncthreads();

    // Each thread's int4 payload is invariant across its grid-stride stores:
    // for i = blk*256 + tid + k*32768, (4i) mod 256 == 4*(tid & 63).
    const int base = lane * 4;
    const int4 v = make_int4(s[base], s[base + 1], s[base + 2], s[base + 3]);
    int4* o4 = (int4*)out;
    for (int i = blockIdx.x * 256 + tid; i < OUT_INT4; i += NBLOCKS * 256) {
        o4[i] = v;
    }
}

extern "C" void kernel_launch(void* const* d_in, const int* in_sizes, int n_in,
                              void* d_out, int out_size, void* d_ws, size_t ws_size,
                              hipStream_t stream) {
    // inputs: 0=input_values (B,L,D) f32, 1=W (Q,D) f32, 2=code_book (C,Q) f32, 3=raw_signal
    const float* code_book = (const float*)d_in[2];
    int* out = (int*)d_out;
    rpq_fused<<<NBLOCKS, 256, 0, stream>>>(code_book, out);
}

// Round 4
// 67.858 us; speedup vs baseline: 1.2369x; 1.2369x over previous
//
#include <hip/hip_runtime.h>

// labels[b,l,c] = argmin_q ( LN(t)[b,l,c] - LN(code_book)[c,q] )
//              = argmax_q LN(code_book)[c,q]        (tn constant along q)
//              = argmax_q code_book[c,q]            (global-scalar LN is monotone)
// => output is a 256-entry per-c label vector broadcast over (B, L).
//
// v4 = CONTROL: bit-identical re-run of the proven 68.0 µs v1 kernel to
// separate "4-chain split regressed codegen" (v2/v3 ~83 µs) from
// "cross-session timing drift". Single scan chain, #pragma unroll 8,
// NBLOCKS=128 — exactly the round-0 source.

#define C_DIM 256
#define Q_DIM 256
#define OUT_INT4 (4 * 512 * 256 / 4)   // B*L*C / 4 = 131072 int4 stores
#define NBLOCKS 128

__global__ __launch_bounds__(256) void rpq_fused(const float* __restrict__ cb,
                                                 int* __restrict__ out) {
    __shared__ int s[C_DIM];
    const int tid  = threadIdx.x;
    const int lane = tid & 63;

    // Thread tid scans row tid. Strict > in ascending q order reproduces
    // jnp.argmin's first-index tie-breaking.
    const float4* row4 = (const float4*)(cb + tid * Q_DIM);
    float best = -3.4e38f;
    int bi = 0;
#pragma unroll 8
    for (int j = 0; j < Q_DIM / 4; ++j) {
        float4 v = row4[j];
        int q = j * 4;
        if (v.x > best) { best = v.x; bi = q; }
        if (v.y > best) { best = v.y; bi = q + 1; }
        if (v.z > best) { best = v.z; bi = q + 2; }
        if (v.w > best) { best = v.w; bi = q + 3; }
    }
    s[tid] = bi;
    __syncthreads();

    // Each thread's int4 payload is invariant across its grid-stride stores:
    // for i = blk*256 + tid + k*32768, (4i) mod 256 == 4*(tid & 63).
    const int base = lane * 4;
    const int4 v = make_int4(s[base], s[base + 1], s[base + 2], s[base + 3]);
    int4* o4 = (int4*)out;
    for (int i = blockIdx.x * blockDim.x + tid; i < OUT_INT4; i += NBLOCKS * 256) {
        o4[i] = v;
    }
}

extern "C" void kernel_launch(void* const* d_in, const int* in_sizes, int n_in,
                              void* d_out, int out_size, void* d_ws, size_t ws_size,
                              hipStream_t stream) {
    // inputs: 0=input_values (B,L,D) f32, 1=W (Q,D) f32, 2=code_book (C,Q) f32, 3=raw_signal
    const float* code_book = (const float*)d_in[2];
    int* out = (int*)d_out;
    rpq_fused<<<NBLOCKS, 256, 0, stream>>>(code_book, out);
}